// Round 10
// baseline (364.423 us; speedup 1.0000x reference)
//
#include <hip/hip_runtime.h>
#include <math.h>

// ---------------- problem constants ----------------
#define B_    2
#define CIN_  32
#define H_    64
#define W_    64
#define HP_   57
#define WP_   57
#define NP_   (B_*HP_*WP_)     // 6498 patches
#define NVALS_ 31

// workspace layout (floats)
#define XR_OFF   0              // 2*3*64*64 = 24576 (RAW conv output, pre-BN)
#define FP_OFF   24576          // 24576 fold of patches   } contiguous 32768
#define FG_OFF   49152          // 8192  fold of boundaries} (zeroed by conv)
#define ST_OFF   57344          // 768: 128 wave-partials x 6 stats (plain stores)
#define WS_TOTAL 58112

// ---------------- math helpers (faithful to jnp f32 semantics) ----------------
static __device__ __forceinline__ float mod2pi(float x) {
    const float TP = (float)(2.0 * M_PI);
    float m = fmodf(x, TP);
    return (m < 0.0f) ? (m + TP) : m;
}
static __device__ __forceinline__ float pow35f(float t) {
    float t2 = t * t, t4 = t2 * t2, t8 = t4 * t4, t16 = t8 * t8, t32 = t16 * t16;
    return t32 * t2 * t;
}
static __device__ __forceinline__ float siluf(float x) {
    return x / (1.0f + expf(-x));
}
static __device__ __forceinline__ float wave_sum(float v) {
#pragma unroll
    for (int m = 1; m < 64; m <<= 1) v += __shfl_xor(v, m);
    return v;
}
// exact f32 of linspace(-1,1,8)[k], computed in f64 like np.linspace
static __device__ __forceinline__ float lin_of(int k) {
    return (float)(-1.0 + (double)k * (2.0 / 7.0));
}

// pre-scaled line coefficients with the 1/ETA=100 atan scale FOLDED IN:
// u = X*dx + Y*dy yields 100*line; d returned by dists_at is 100*d_ref.
// (R6/R8 lesson: ocml atanf is the cheapest atan on gfx950 — keep it.)
struct Geo {
    float X1, Y1, X3, Y3;     // pair (a1, a3) for d13
    float X4, Y4, X2, Y2;     // pair (a4, a2) for d42
    float sgn13, sgn42, g13, g42, x0, y0;
};

static __device__ void setup_geo(float p0, float p1, float p2, float p3, float p4,
                                 Geo& G) {
    const float PIF = (float)M_PI;
    const float SC = 100.0f;    // 1/ETA folded into the plane coefficients
    float m0 = mod2pi(p0), m1 = mod2pi(p1), m2 = mod2pi(p2);
    float lo = fminf(m0, m1), hi = fmaxf(m0, m1);
    float a1 = fminf(lo, m2);
    float a3 = fmaxf(hi, m2);
    float a2 = fmaxf(fminf(hi, m2), lo);
    float hm = mod2pi(0.5f * (a1 - a3));
    float a4 = 0.5f * (a1 + a3) + ((hm >= PIF) ? PIF : 0.0f);
    float d42 = mod2pi(a2 - a4);
    G.sgn42 = (d42 < PIF) ? 1.0f : -1.0f;
    G.g42 = pow35f(d42 / PIF - 1.0f) * 10.0f;   // TAU(0.1) * 100
    float d13 = mod2pi(a3 - a1);
    G.sgn13 = (d13 < PIF) ? 1.0f : -1.0f;
    G.g13 = pow35f(d13 / PIF - 1.0f) * 10.0f;
    float s1 = sinf(a1), c1 = cosf(a1);
    float s2 = sinf(a2), c2 = cosf(a2);
    float s3 = sinf(a3), c3 = cosf(a3);
    float s4 = sinf(a4), c4 = cosf(a4);
    G.X1 = -G.sgn13 * s1 * SC;  G.Y1 =  G.sgn13 * c1 * SC;
    G.X3 =  G.sgn13 * s3 * SC;  G.Y3 = -G.sgn13 * c3 * SC;
    G.X4 = -G.sgn42 * s4 * SC;  G.Y4 =  G.sgn42 * c4 * SC;
    G.X2 =  G.sgn42 * s2 * SC;  G.Y2 = -G.sgn42 * c2 * SC;
    G.x0 = p3; G.y0 = p4;
}

// returns 100*d13, 100*d42
static __device__ __forceinline__ void dists_at(const Geo& G, float xg, float yg,
                                                float& d13, float& d42) {
    float dx = xg - G.x0, dy = yg - G.y0;
    float u1 = G.X1 * dx + G.Y1 * dy;
    float u3 = G.X3 * dx + G.Y3 * dy;
    float u4 = G.X4 * dx + G.Y4 * dy;
    float u2 = G.X2 * dx + G.Y2 * dy;
    d13 = G.sgn13 * fminf(u1, u3) + G.g13;
    d42 = G.sgn42 * fminf(u4, u2) + G.g42;
}

// inputs are pre-scaled (100*d): atan arg needs no multiply
static __device__ __forceinline__ void wedge_of(float d13s, float d42s,
                                                float& w0, float& w1, float& w2) {
    const float C2OPI = (float)(2.0 / M_PI);
    float hd0 = 0.5f * (1.0f + C2OPI * atanf(d13s));
    float hd1 = 0.5f * (1.0f + C2OPI * atanf(d42s));
    w0 = 1.0f - hd0;
    w1 = hd0 * (1.0f - hd1);
    w2 = hd0 * hd1;
}

// ---------------- kernel A: conv1x1 + BN wave-partials + zero fold buffers --
__global__ __launch_bounds__(128) void head_in_conv(const float* __restrict__ x,
                                                    const float* __restrict__ rw,
                                                    float* __restrict__ xr,
                                                    float* __restrict__ st,
                                                    float4* __restrict__ foldZ) {
    const int e = blockIdx.x * 128 + threadIdx.x;   // 0..8191
    // zero foldP+foldG (32768 floats = 8192 float4, contiguous)
    foldZ[e] = make_float4(0.0f, 0.0f, 0.0f, 0.0f);
    const int b = e >> 12, rem = e & 4095;
    const float* xp = x + (size_t)b * CIN_ * 4096 + rem;
    float a0 = 0.0f, a1 = 0.0f, a2 = 0.0f;
#pragma unroll
    for (int c = 0; c < CIN_; ++c) {
        float xv = xp[c * 4096];
        a0 += rw[c] * xv;
        a1 += rw[32 + c] * xv;
        a2 += rw[64 + c] * xv;
    }
    xr[(b * 3 + 0) * 4096 + rem] = a0;
    xr[(b * 3 + 1) * 4096 + rem] = a1;
    xr[(b * 3 + 2) * 4096 + rem] = a2;
    float s0 = wave_sum(a0), q0 = wave_sum(a0 * a0);
    float s1 = wave_sum(a1), q1 = wave_sum(a1 * a1);
    float s2 = wave_sum(a2), q2 = wave_sum(a2 * a2);
    if ((threadIdx.x & 63) == 0) {
        const int wv = (blockIdx.x << 1) | (threadIdx.x >> 6);  // 0..127
        float* dst = st + wv * 6;
        dst[0] = s0; dst[1] = s1; dst[2] = s2;
        dst[3] = q0; dst[4] = q1; dst[5] = q2;
    }
}

// ---------------- mega kernel: stats-reduce + BN-apply + 5-step + finalize --
// wave = 1 patch; 4 patches / 256-thread block.
// __launch_bounds__(256,6): pin 6 waves/SIMD (<=85 VGPR) — R9 lesson: the
// dxv[8] hoist pushed VGPR 84->104, dropping 6->4 waves/SIMD and costing more
// latency-hiding than the saved LDS reads were worth. Recompute dx in-loop.
__global__ __launch_bounds__(256, 6) void mega_kernel(const float* __restrict__ xr,
                                                      const float* __restrict__ gamma,
                                                      const float* __restrict__ beta,
                                                      const float* __restrict__ st,
                                                      float* __restrict__ foldP,
                                                      float* __restrict__ foldG) {
    __shared__ float s_img[4][192];   // 4 patches per block, [c*64 + pix]
    __shared__ float s_lin[8];
    const int t = threadIdx.x;
    if (t < 8) s_lin[t] = lin_of(t);
    const int lg = t >> 6, lane = t & 63;
    const int patch = blockIdx.x * 4 + lg;
    const bool active = (patch < NP_);

    // reduce 128 BN wave-partials (plain-stored by conv) -> all lanes hold sums
    float s0, s1, s2, q0, q1, q2;
    {
        const float* pa = st + lane * 6;
        const float* pb = st + (lane + 64) * 6;
        s0 = wave_sum(pa[0] + pb[0]);
        s1 = wave_sum(pa[1] + pb[1]);
        s2 = wave_sum(pa[2] + pb[2]);
        q0 = wave_sum(pa[3] + pb[3]);
        q1 = wave_sum(pa[4] + pb[4]);
        q2 = wave_sum(pa[5] + pb[5]);
    }

    int b = 0, hp = 0, wp = 0;
    if (active) {
        b = patch / (HP_ * WP_);
        int pi = patch - b * (HP_ * WP_);
        hp = pi / WP_; wp = pi - hp * WP_;
        const int pr = lane >> 3, pc = lane & 7;
        const int goff = ((hp + pr) << 6) + (wp + pc);
        float mean0 = s0 / 8192.0f, var0 = q0 / 8192.0f - mean0 * mean0;
        float mean1 = s1 / 8192.0f, var1 = q1 / 8192.0f - mean1 * mean1;
        float mean2 = s2 / 8192.0f, var2 = q2 / 8192.0f - mean2 * mean2;
        float sc0 = gamma[0] / sqrtf(var0 + 1e-5f), sh0 = beta[0] - mean0 * sc0;
        float sc1 = gamma[1] / sqrtf(var1 + 1e-5f), sh1 = beta[1] - mean1 * sc1;
        float sc2 = gamma[2] / sqrtf(var2 + 1e-5f), sh2 = beta[2] - mean2 * sc2;
        s_img[lg][lane]       = siluf(xr[((b * 3 + 0) << 12) + goff] * sc0 + sh0);
        s_img[lg][64 + lane]  = siluf(xr[((b * 3 + 1) << 12) + goff] * sc1 + sh1);
        s_img[lg][128 + lane] = siluf(xr[((b * 3 + 2) << 12) + goff] * sc2 + sh2);
    }
    __syncthreads();
    if (!active) return;

    const int cand = lane >> 1;     // 0..31 (31 is padding)
    const int half = lane & 1;      // pixel-half
    const float* img = s_img[lg] + half * 32;
    const int yoff = half << 2;

    // patch sums: candidate- and step-invariant — computed ONCE
    float is0 = 0, is1 = 0, is2 = 0;
#pragma unroll
    for (int i = 0; i < 32; ++i) {
        is0 += img[i]; is1 += img[64 + i]; is2 += img[128 + i];
    }
    is0 += __shfl_xor(is0, 1); is1 += __shfl_xor(is1, 1); is2 += __shfl_xor(is2, 1);

    float p0 = 0.0f, p1 = 0.0f, p2 = 0.0f, p3 = 0.0f, p4 = 0.0f;

#pragma unroll 1
    for (int step = 0; step < 5; ++step) {
        const float base = (step == 0) ? p0 : (step == 1) ? p1 :
                           (step == 2) ? p2 : (step == 3) ? p3 : p4;
        const int ci = (cand < NVALS_) ? cand : (NVALS_ - 1);
        float add;
        if (step < 3) add = (float)((double)ci * (6.283185307179586476925286766559 / 31.0));
        else          add = (float)(-3.0 + (double)ci * 0.2);
        const float pv = base + add;
        Geo G;
        setup_geo((step == 0) ? pv : p0, (step == 1) ? pv : p1,
                  (step == 2) ? pv : p2, (step == 3) ? pv : p3,
                  (step == 4) ? pv : p4, G);

        float ws0 = 0, ws1 = 0;
        float cn00 = 0, cn01 = 0, cn10 = 0, cn11 = 0, cn20 = 0, cn21 = 0;
        float g00 = 0, g01 = 0, g11 = 0;
#pragma unroll 1
        for (int r = 0; r < 4; ++r) {
            const float yg = s_lin[yoff + r];
            const float dy = yg - G.y0;
            const float t1 = G.Y1 * dy, t3 = G.Y3 * dy;
            const float t4 = G.Y4 * dy, t2 = G.Y2 * dy;
#pragma unroll
            for (int cth = 0; cth < 8; ++cth) {
                const int i = r * 8 + cth;
                const float dx = s_lin[cth] - G.x0;    // LDS broadcast, cheap
                float u1 = G.X1 * dx + t1;
                float u3 = G.X3 * dx + t3;
                float u4 = G.X4 * dx + t4;
                float u2 = G.X2 * dx + t2;
                float d13 = G.sgn13 * fminf(u1, u3) + G.g13;   // pre-scaled
                float d42 = G.sgn42 * fminf(u4, u2) + G.g42;
                float w0, w1, w2;
                wedge_of(d13, d42, w0, w1, w2);
                float i0 = img[i], i1 = img[64 + i], i2 = img[128 + i];
                ws0 += w0; ws1 += w1;
                cn00 += i0 * w0; cn01 += i0 * w1;
                cn10 += i1 * w0; cn11 += i1 * w1;
                cn20 += i2 * w0; cn21 += i2 * w1;
                g00 += w0 * w0; g01 += w0 * w1; g11 += w1 * w1;
            }
        }
        // combine pixel-halves (xor-1: cheap swizzle path)
        ws0 += __shfl_xor(ws0, 1); ws1 += __shfl_xor(ws1, 1);
        cn00 += __shfl_xor(cn00, 1); cn01 += __shfl_xor(cn01, 1);
        cn10 += __shfl_xor(cn10, 1); cn11 += __shfl_xor(cn11, 1);
        cn20 += __shfl_xor(cn20, 1); cn21 += __shfl_xor(cn21, 1);
        g00 += __shfl_xor(g00, 1); g01 += __shfl_xor(g01, 1); g11 += __shfl_xor(g11, 1);

        // derive dependent sums (partition of unity)
        float ws2  = 64.0f - ws0 - ws1;
        float cn02 = is0 - cn00 - cn01;
        float cn12 = is1 - cn10 - cn11;
        float cn22 = is2 - cn20 - cn21;
        float g02  = ws0 - g00 - g01;
        float g12  = ws1 - g01 - g11;
        float g22  = ws2 - g02 - g12;

        float r0 = 1.0f / (ws0 + 1e-10f);
        float r1 = 1.0f / (ws1 + 1e-10f);
        float r2 = 1.0f / (ws2 + 1e-10f);
        float c00 = cn00 * r0, c01 = cn01 * r1, c02 = cn02 * r2;
        float c10 = cn10 * r0, c11 = cn11 * r1, c12 = cn12 * r2;
        float c20 = cn20 * r0, c21 = cn21 * r1, c22 = cn22 * r2;

        // loss' = col^T G col - 2 col.cn (constant Sum(i^2) dropped)
        float loss =
            (c00 * c00 * g00 + c01 * c01 * g11 + c02 * c02 * g22
             + 2.0f * (c00 * c01 * g01 + c00 * c02 * g02 + c01 * c02 * g12)
             - 2.0f * (c00 * cn00 + c01 * cn01 + c02 * cn02))
          + (c10 * c10 * g00 + c11 * c11 * g11 + c12 * c12 * g22
             + 2.0f * (c10 * c11 * g01 + c10 * c12 * g02 + c11 * c12 * g12)
             - 2.0f * (c10 * cn10 + c11 * cn11 + c12 * cn12))
          + (c20 * c20 * g00 + c21 * c21 * g11 + c22 * c22 * g22
             + 2.0f * (c20 * c21 * g01 + c20 * c22 * g02 + c21 * c22 * g12)
             - 2.0f * (c20 * cn20 + c21 * cn21 + c22 * cn22));
        if (cand >= NVALS_) loss = INFINITY;

        // argmin over the wave (half-pairs identical; ties -> lower cand)
        float bl = loss; int bi = cand;
#pragma unroll
        for (int off = 32; off > 0; off >>= 1) {
            float ol = __shfl_down(bl, (unsigned)off);
            int   oi = __shfl_down(bi, (unsigned)off);
            if (ol < bl || (ol == bl && oi < bi)) { bl = ol; bi = oi; }
        }
        bi = __shfl(bi, 0);   // broadcast winner to all lanes
        float badd;
        if (step < 3) badd = (float)((double)bi * (6.283185307179586476925286766559 / 31.0));
        else          badd = (float)(-3.0 + (double)bi * 0.2);
        const float bv = base + badd;
        if (step == 0) p0 = bv; else if (step == 1) p1 = bv;
        else if (step == 2) p2 = bv; else if (step == 3) p3 = bv; else p4 = bv;
    }

    // ---------------- finalize + fold (lane = pixel) ----------------
    {
        Geo G; setup_geo(p0, p1, p2, p3, p4, G);
        const int pr = lane >> 3, pc = lane & 7;
        float xg = s_lin[pc], yg = s_lin[pr];
        float d13, d42;                         // pre-scaled (100*d)
        dists_at(G, xg, yg, d13, d42);
        float w0, w1, w2;
        wedge_of(d13, d42, w0, w1, w2);
        float i0 = s_img[lg][lane];
        float i1 = s_img[lg][64 + lane];
        float i2 = s_img[lg][128 + lane];

        float r[12] = { w0, w1, w2,
                        i0 * w0, i0 * w1, i0 * w2,
                        i1 * w0, i1 * w1, i1 * w2,
                        i2 * w0, i2 * w1, i2 * w2 };
#pragma unroll
        for (int m = 1; m < 64; m <<= 1) {
#pragma unroll
            for (int j = 0; j < 12; ++j) r[j] += __shfl_xor(r[j], m);
        }
        float col[3][3];
#pragma unroll
        for (int c = 0; c < 3; ++c) {
            col[c][0] = r[3 + c * 3 + 0] / (r[0] + 1e-10f);
            col[c][1] = r[3 + c * 3 + 1] / (r[1] + 1e-10f);
            col[c][2] = r[3 + c * 3 + 2] / (r[2] + 1e-10f);
        }
        float o0 = w0 * col[0][0] + w1 * col[0][1] + w2 * col[0][2];
        float o1 = w0 * col[1][0] + w1 * col[1][1] + w2 * col[1][2];
        float o2 = w0 * col[2][0] + w1 * col[2][1] + w2 * col[2][2];

        // mad on the 100x scale; tt = mad/DELTA = mad_s * (1/(100*0.05))
        float mad = (d13 < 0.0f) ? -d13 : ((d42 < 0.0f) ? fminf(d13, -d42) : fminf(d13, d42));
        float tt = mad * 0.2f;
        float lb = 1.0f / (1.0f + tt * tt);

        const int off = ((hp + pr) << 6) + (wp + pc);
        atomicAdd(&foldP[(b * 3 + 0) * 4096 + off], o0);
        atomicAdd(&foldP[(b * 3 + 1) * 4096 + off], o1);
        atomicAdd(&foldP[(b * 3 + 2) * 4096 + off], o2);
        atomicAdd(&foldG[b * 4096 + off], lb);
    }
}

// ---------------- kernel D: fused output heads (ONE block, LDS staging) -----
static __device__ __forceinline__ float np_count(int tpos) {
    int lo = (tpos - 56 > 0) ? (tpos - 56) : 0;
    int hi = (tpos < 7) ? tpos : 7;
    return (float)(hi - lo + 1);
}

__global__ __launch_bounds__(1024) void head_out(const float* __restrict__ foldP,
                                                 const float* __restrict__ foldG,
                                                 const float* __restrict__ fb_w,
                                                 const float* __restrict__ fb_g,
                                                 const float* __restrict__ fb_b,
                                                 const float* __restrict__ fi_w,
                                                 const float* __restrict__ fi_g,
                                                 const float* __restrict__ fi_b,
                                                 float* __restrict__ out) {
    __shared__ float sB[8192];     // 32 KB
    __shared__ float sI[8192];     // 32 KB
    __shared__ float red[16][4];
    __shared__ float s_sc[4];      // scB, shB, scI, shI
    const int t = threadIdx.x;
    float sb = 0, qb = 0, si = 0, qi = 0;
#pragma unroll
    for (int k = 0; k < 8; ++k) {
        const int e = t + 1024 * k;
        const int b = e >> 12, h = (e >> 6) & 63, w = e & 63;
        const float inv = 1.0f / (np_count(h) * np_count(w));
        float gv = foldG[e] * inv;
        float vb = fb_w[0] * gv + fb_w[1] * gv + fb_w[2] * gv;
        const int off = (h << 6) + w;
        float v0 = foldP[(b * 3 + 0) * 4096 + off] * inv;
        float v1 = foldP[(b * 3 + 1) * 4096 + off] * inv;
        float v2 = foldP[(b * 3 + 2) * 4096 + off] * inv;
        float vi = fi_w[0] * v0 + fi_w[1] * v1 + fi_w[2] * v2;
        sB[e] = vb; sI[e] = vi;
        sb += vb; qb += vb * vb; si += vi; qi += vi * vi;
    }
    sb = wave_sum(sb); qb = wave_sum(qb); si = wave_sum(si); qi = wave_sum(qi);
    const int wid = t >> 6;
    if ((t & 63) == 0) { red[wid][0] = sb; red[wid][1] = qb; red[wid][2] = si; red[wid][3] = qi; }
    __syncthreads();
    if (t == 0) {
        float S = 0, Q = 0, S2 = 0, Q2 = 0;
#pragma unroll
        for (int w = 0; w < 16; ++w) { S += red[w][0]; Q += red[w][1]; S2 += red[w][2]; Q2 += red[w][3]; }
        float meanB = S / 8192.0f,  varB = Q / 8192.0f - meanB * meanB;
        float meanI = S2 / 8192.0f, varI = Q2 / 8192.0f - meanI * meanI;
        float scB = fb_g[0] / sqrtf(varB + 1e-5f);
        float scI = fi_g[0] / sqrtf(varI + 1e-5f);
        s_sc[0] = scB; s_sc[1] = fb_b[0] - meanB * scB;
        s_sc[2] = scI; s_sc[3] = fi_b[0] - meanI * scI;
    }
    __syncthreads();
    const float scB = s_sc[0], shB = s_sc[1], scI = s_sc[2], shI = s_sc[3];
#pragma unroll
    for (int k = 0; k < 8; ++k) {
        const int e = t + 1024 * k;
        out[e]        = siluf(sB[e] * scB + shB);
        out[8192 + e] = siluf(sI[e] * scI + shI);
    }
}

// ---------------- launch (3 dispatches, no memset) ----------------
extern "C" void kernel_launch(void* const* d_in, const int* in_sizes, int n_in,
                              void* d_out, int out_size, void* d_ws, size_t ws_size,
                              hipStream_t stream) {
    (void)in_sizes; (void)n_in; (void)out_size; (void)ws_size;
    const float* x        = (const float*)d_in[0];
    const float* reduce_w = (const float*)d_in[1];
    const float* reduce_g = (const float*)d_in[2];
    const float* reduce_b = (const float*)d_in[3];
    const float* fb_w     = (const float*)d_in[4];
    const float* fb_g     = (const float*)d_in[5];
    const float* fb_b     = (const float*)d_in[6];
    const float* fi_w     = (const float*)d_in[7];
    const float* fi_g     = (const float*)d_in[8];
    const float* fi_b     = (const float*)d_in[9];
    float* ws     = (float*)d_ws;
    float* xr     = ws + XR_OFF;
    float* foldP  = ws + FP_OFF;
    float* foldG  = ws + FG_OFF;
    float* st     = ws + ST_OFF;
    float* out    = (float*)d_out;

    head_in_conv<<<64, 128, 0, stream>>>(x, reduce_w, xr, st, (float4*)foldP);
    mega_kernel<<<(NP_ + 3) / 4, 256, 0, stream>>>(xr, reduce_g, reduce_b, st,
                                                   foldP, foldG);
    head_out<<<1, 1024, 0, stream>>>(foldP, foldG, fb_w, fb_g, fb_b,
                                     fi_w, fi_g, fi_b, out);
}

// Round 11
// 237.368 us; speedup vs baseline: 1.5353x; 1.5353x over previous
//
#include <hip/hip_runtime.h>
#include <math.h>

// ---------------- problem constants ----------------
#define B_    2
#define CIN_  32
#define H_    64
#define W_    64
#define HP_   57
#define WP_   57
#define NP_   (B_*HP_*WP_)     // 6498 patches
#define NVALS_ 31

// workspace layout (floats)
#define XR_OFF   0              // 2*3*64*64 = 24576 (RAW conv output, pre-BN)
#define FP_OFF   24576          // 24576 fold of patches   } contiguous 32768
#define FG_OFF   49152          // 8192  fold of boundaries} (zeroed by conv)
#define ST_OFF   57344          // 768: 128 wave-partials x 6 stats (plain stores)
#define WS_TOTAL 58112

// ---------------- math helpers (faithful to jnp f32 semantics) ----------------
static __device__ __forceinline__ float mod2pi(float x) {
    const float TP = (float)(2.0 * M_PI);
    float m = fmodf(x, TP);
    return (m < 0.0f) ? (m + TP) : m;
}
static __device__ __forceinline__ float pow35f(float t) {
    float t2 = t * t, t4 = t2 * t2, t8 = t4 * t4, t16 = t8 * t8, t32 = t16 * t16;
    return t32 * t2 * t;
}
static __device__ __forceinline__ float siluf(float x) {
    return x / (1.0f + expf(-x));
}
static __device__ __forceinline__ float wave_sum(float v) {
#pragma unroll
    for (int m = 1; m < 64; m <<= 1) v += __shfl_xor(v, m);
    return v;
}
// exact f32 of linspace(-1,1,8)[k], computed in f64 like np.linspace
static __device__ __forceinline__ float lin_of(int k) {
    return (float)(-1.0 + (double)k * (2.0 / 7.0));
}

// pre-scaled line coefficients with the 1/ETA=100 atan scale FOLDED IN:
// u = X*dx + Y*dy yields 100*line; d returned by dists_at is 100*d_ref.
// (R6/R8 lesson: ocml atanf is the cheapest atan on gfx950 — keep it.
//  R10 lesson: NEVER pin occupancy via __launch_bounds__ second arg here —
//  forcing 6 waves/SIMD collapsed the allocator to 40 VGPR + 830 MB spill.)
struct Geo {
    float X1, Y1, X3, Y3;     // pair (a1, a3) for d13
    float X4, Y4, X2, Y2;     // pair (a4, a2) for d42
    float sgn13, sgn42, g13, g42, x0, y0;
};

static __device__ void setup_geo(float p0, float p1, float p2, float p3, float p4,
                                 Geo& G) {
    const float PIF = (float)M_PI;
    const float SC = 100.0f;    // 1/ETA folded into the plane coefficients
    float m0 = mod2pi(p0), m1 = mod2pi(p1), m2 = mod2pi(p2);
    float lo = fminf(m0, m1), hi = fmaxf(m0, m1);
    float a1 = fminf(lo, m2);
    float a3 = fmaxf(hi, m2);
    float a2 = fmaxf(fminf(hi, m2), lo);
    float hm = mod2pi(0.5f * (a1 - a3));
    float a4 = 0.5f * (a1 + a3) + ((hm >= PIF) ? PIF : 0.0f);
    float d42 = mod2pi(a2 - a4);
    G.sgn42 = (d42 < PIF) ? 1.0f : -1.0f;
    G.g42 = pow35f(d42 / PIF - 1.0f) * 10.0f;   // TAU(0.1) * 100
    float d13 = mod2pi(a3 - a1);
    G.sgn13 = (d13 < PIF) ? 1.0f : -1.0f;
    G.g13 = pow35f(d13 / PIF - 1.0f) * 10.0f;
    float s1 = sinf(a1), c1 = cosf(a1);
    float s2 = sinf(a2), c2 = cosf(a2);
    float s3 = sinf(a3), c3 = cosf(a3);
    float s4 = sinf(a4), c4 = cosf(a4);
    G.X1 = -G.sgn13 * s1 * SC;  G.Y1 =  G.sgn13 * c1 * SC;
    G.X3 =  G.sgn13 * s3 * SC;  G.Y3 = -G.sgn13 * c3 * SC;
    G.X4 = -G.sgn42 * s4 * SC;  G.Y4 =  G.sgn42 * c4 * SC;
    G.X2 =  G.sgn42 * s2 * SC;  G.Y2 = -G.sgn42 * c2 * SC;
    G.x0 = p3; G.y0 = p4;
}

// returns 100*d13, 100*d42
static __device__ __forceinline__ void dists_at(const Geo& G, float xg, float yg,
                                                float& d13, float& d42) {
    float dx = xg - G.x0, dy = yg - G.y0;
    float u1 = G.X1 * dx + G.Y1 * dy;
    float u3 = G.X3 * dx + G.Y3 * dy;
    float u4 = G.X4 * dx + G.Y4 * dy;
    float u2 = G.X2 * dx + G.Y2 * dy;
    d13 = G.sgn13 * fminf(u1, u3) + G.g13;
    d42 = G.sgn42 * fminf(u4, u2) + G.g42;
}

// inputs are pre-scaled (100*d): atan arg needs no multiply
static __device__ __forceinline__ void wedge_of(float d13s, float d42s,
                                                float& w0, float& w1, float& w2) {
    const float C2OPI = (float)(2.0 / M_PI);
    float hd0 = 0.5f * (1.0f + C2OPI * atanf(d13s));
    float hd1 = 0.5f * (1.0f + C2OPI * atanf(d42s));
    w0 = 1.0f - hd0;
    w1 = hd0 * (1.0f - hd1);
    w2 = hd0 * hd1;
}

// ---------------- kernel A: conv1x1 + BN wave-partials + zero fold buffers --
__global__ __launch_bounds__(128) void head_in_conv(const float* __restrict__ x,
                                                    const float* __restrict__ rw,
                                                    float* __restrict__ xr,
                                                    float* __restrict__ st,
                                                    float4* __restrict__ foldZ) {
    const int e = blockIdx.x * 128 + threadIdx.x;   // 0..8191
    // zero foldP+foldG (32768 floats = 8192 float4, contiguous)
    foldZ[e] = make_float4(0.0f, 0.0f, 0.0f, 0.0f);
    const int b = e >> 12, rem = e & 4095;
    const float* xp = x + (size_t)b * CIN_ * 4096 + rem;
    float a0 = 0.0f, a1 = 0.0f, a2 = 0.0f;
#pragma unroll
    for (int c = 0; c < CIN_; ++c) {
        float xv = xp[c * 4096];
        a0 += rw[c] * xv;
        a1 += rw[32 + c] * xv;
        a2 += rw[64 + c] * xv;
    }
    xr[(b * 3 + 0) * 4096 + rem] = a0;
    xr[(b * 3 + 1) * 4096 + rem] = a1;
    xr[(b * 3 + 2) * 4096 + rem] = a2;
    float s0 = wave_sum(a0), q0 = wave_sum(a0 * a0);
    float s1 = wave_sum(a1), q1 = wave_sum(a1 * a1);
    float s2 = wave_sum(a2), q2 = wave_sum(a2 * a2);
    if ((threadIdx.x & 63) == 0) {
        const int wv = (blockIdx.x << 1) | (threadIdx.x >> 6);  // 0..127
        float* dst = st + wv * 6;
        dst[0] = s0; dst[1] = s1; dst[2] = s2;
        dst[3] = q0; dst[4] = q1; dst[5] = q2;
    }
}

// ---------------- mega kernel: stats-reduce + BN-apply + 5-step + finalize --
// wave = 1 patch; 4 patches / 256-thread block. NATURAL register allocation
// (plain launch_bounds) — R10 proved pinning spills catastrophically.
__global__ __launch_bounds__(256) void mega_kernel(const float* __restrict__ xr,
                                                   const float* __restrict__ gamma,
                                                   const float* __restrict__ beta,
                                                   const float* __restrict__ st,
                                                   float* __restrict__ foldP,
                                                   float* __restrict__ foldG) {
    __shared__ float s_img[4][192];   // 4 patches per block, [c*64 + pix]
    __shared__ float s_lin[8];
    const int t = threadIdx.x;
    if (t < 8) s_lin[t] = lin_of(t);
    const int lg = t >> 6, lane = t & 63;
    const int patch = blockIdx.x * 4 + lg;
    const bool active = (patch < NP_);

    // reduce 128 BN wave-partials (plain-stored by conv) -> all lanes hold sums
    float s0, s1, s2, q0, q1, q2;
    {
        const float* pa = st + lane * 6;
        const float* pb = st + (lane + 64) * 6;
        s0 = wave_sum(pa[0] + pb[0]);
        s1 = wave_sum(pa[1] + pb[1]);
        s2 = wave_sum(pa[2] + pb[2]);
        q0 = wave_sum(pa[3] + pb[3]);
        q1 = wave_sum(pa[4] + pb[4]);
        q2 = wave_sum(pa[5] + pb[5]);
    }

    int b = 0, hp = 0, wp = 0;
    if (active) {
        b = patch / (HP_ * WP_);
        int pi = patch - b * (HP_ * WP_);
        hp = pi / WP_; wp = pi - hp * WP_;
        const int pr = lane >> 3, pc = lane & 7;
        const int goff = ((hp + pr) << 6) + (wp + pc);
        float mean0 = s0 / 8192.0f, var0 = q0 / 8192.0f - mean0 * mean0;
        float mean1 = s1 / 8192.0f, var1 = q1 / 8192.0f - mean1 * mean1;
        float mean2 = s2 / 8192.0f, var2 = q2 / 8192.0f - mean2 * mean2;
        float sc0 = gamma[0] / sqrtf(var0 + 1e-5f), sh0 = beta[0] - mean0 * sc0;
        float sc1 = gamma[1] / sqrtf(var1 + 1e-5f), sh1 = beta[1] - mean1 * sc1;
        float sc2 = gamma[2] / sqrtf(var2 + 1e-5f), sh2 = beta[2] - mean2 * sc2;
        s_img[lg][lane]       = siluf(xr[((b * 3 + 0) << 12) + goff] * sc0 + sh0);
        s_img[lg][64 + lane]  = siluf(xr[((b * 3 + 1) << 12) + goff] * sc1 + sh1);
        s_img[lg][128 + lane] = siluf(xr[((b * 3 + 2) << 12) + goff] * sc2 + sh2);
    }
    __syncthreads();
    if (!active) return;

    const int cand = lane >> 1;     // 0..31 (31 is padding)
    const int half = lane & 1;      // pixel-half
    const float* img = s_img[lg] + half * 32;
    const int yoff = half << 2;

    // patch sums: candidate- and step-invariant — computed ONCE
    float is0 = 0, is1 = 0, is2 = 0;
#pragma unroll
    for (int i = 0; i < 32; ++i) {
        is0 += img[i]; is1 += img[64 + i]; is2 += img[128 + i];
    }
    is0 += __shfl_xor(is0, 1); is1 += __shfl_xor(is1, 1); is2 += __shfl_xor(is2, 1);

    float p0 = 0.0f, p1 = 0.0f, p2 = 0.0f, p3 = 0.0f, p4 = 0.0f;

#pragma unroll 1
    for (int step = 0; step < 5; ++step) {
        const float base = (step == 0) ? p0 : (step == 1) ? p1 :
                           (step == 2) ? p2 : (step == 3) ? p3 : p4;
        const int ci = (cand < NVALS_) ? cand : (NVALS_ - 1);
        float add;
        if (step < 3) add = (float)((double)ci * (6.283185307179586476925286766559 / 31.0));
        else          add = (float)(-3.0 + (double)ci * 0.2);
        const float pv = base + add;
        Geo G;
        setup_geo((step == 0) ? pv : p0, (step == 1) ? pv : p1,
                  (step == 2) ? pv : p2, (step == 3) ? pv : p3,
                  (step == 4) ? pv : p4, G);

        float ws0 = 0, ws1 = 0;
        float cn00 = 0, cn01 = 0, cn10 = 0, cn11 = 0, cn20 = 0, cn21 = 0;
        float g00 = 0, g01 = 0, g11 = 0;
#pragma unroll 1
        for (int r = 0; r < 4; ++r) {
            const float yg = s_lin[yoff + r];
            const float dy = yg - G.y0;
            const float t1 = G.Y1 * dy, t3 = G.Y3 * dy;
            const float t4 = G.Y4 * dy, t2 = G.Y2 * dy;
#pragma unroll
            for (int cth = 0; cth < 8; ++cth) {
                const int i = r * 8 + cth;
                const float dx = s_lin[cth] - G.x0;    // LDS broadcast, cheap
                float u1 = G.X1 * dx + t1;
                float u3 = G.X3 * dx + t3;
                float u4 = G.X4 * dx + t4;
                float u2 = G.X2 * dx + t2;
                float d13 = G.sgn13 * fminf(u1, u3) + G.g13;   // pre-scaled
                float d42 = G.sgn42 * fminf(u4, u2) + G.g42;
                float w0, w1, w2;
                wedge_of(d13, d42, w0, w1, w2);
                float i0 = img[i], i1 = img[64 + i], i2 = img[128 + i];
                ws0 += w0; ws1 += w1;
                cn00 += i0 * w0; cn01 += i0 * w1;
                cn10 += i1 * w0; cn11 += i1 * w1;
                cn20 += i2 * w0; cn21 += i2 * w1;
                g00 += w0 * w0; g01 += w0 * w1; g11 += w1 * w1;
            }
        }
        // combine pixel-halves (xor-1: cheap swizzle path)
        ws0 += __shfl_xor(ws0, 1); ws1 += __shfl_xor(ws1, 1);
        cn00 += __shfl_xor(cn00, 1); cn01 += __shfl_xor(cn01, 1);
        cn10 += __shfl_xor(cn10, 1); cn11 += __shfl_xor(cn11, 1);
        cn20 += __shfl_xor(cn20, 1); cn21 += __shfl_xor(cn21, 1);
        g00 += __shfl_xor(g00, 1); g01 += __shfl_xor(g01, 1); g11 += __shfl_xor(g11, 1);

        // derive dependent sums (partition of unity)
        float ws2  = 64.0f - ws0 - ws1;
        float cn02 = is0 - cn00 - cn01;
        float cn12 = is1 - cn10 - cn11;
        float cn22 = is2 - cn20 - cn21;
        float g02  = ws0 - g00 - g01;
        float g12  = ws1 - g01 - g11;
        float g22  = ws2 - g02 - g12;

        float r0 = 1.0f / (ws0 + 1e-10f);
        float r1 = 1.0f / (ws1 + 1e-10f);
        float r2 = 1.0f / (ws2 + 1e-10f);
        float c00 = cn00 * r0, c01 = cn01 * r1, c02 = cn02 * r2;
        float c10 = cn10 * r0, c11 = cn11 * r1, c12 = cn12 * r2;
        float c20 = cn20 * r0, c21 = cn21 * r1, c22 = cn22 * r2;

        // loss' = col^T G col - 2 col.cn (constant Sum(i^2) dropped)
        float loss =
            (c00 * c00 * g00 + c01 * c01 * g11 + c02 * c02 * g22
             + 2.0f * (c00 * c01 * g01 + c00 * c02 * g02 + c01 * c02 * g12)
             - 2.0f * (c00 * cn00 + c01 * cn01 + c02 * cn02))
          + (c10 * c10 * g00 + c11 * c11 * g11 + c12 * c12 * g22
             + 2.0f * (c10 * c11 * g01 + c10 * c12 * g02 + c11 * c12 * g12)
             - 2.0f * (c10 * cn10 + c11 * cn11 + c12 * cn12))
          + (c20 * c20 * g00 + c21 * c21 * g11 + c22 * c22 * g22
             + 2.0f * (c20 * c21 * g01 + c20 * c22 * g02 + c21 * c22 * g12)
             - 2.0f * (c20 * cn20 + c21 * cn21 + c22 * cn22));
        if (cand >= NVALS_) loss = INFINITY;

        // argmin over the wave (half-pairs identical; ties -> lower cand)
        float bl = loss; int bi = cand;
#pragma unroll
        for (int off = 32; off > 0; off >>= 1) {
            float ol = __shfl_down(bl, (unsigned)off);
            int   oi = __shfl_down(bi, (unsigned)off);
            if (ol < bl || (ol == bl && oi < bi)) { bl = ol; bi = oi; }
        }
        bi = __shfl(bi, 0);   // broadcast winner to all lanes
        float badd;
        if (step < 3) badd = (float)((double)bi * (6.283185307179586476925286766559 / 31.0));
        else          badd = (float)(-3.0 + (double)bi * 0.2);
        const float bv = base + badd;
        if (step == 0) p0 = bv; else if (step == 1) p1 = bv;
        else if (step == 2) p2 = bv; else if (step == 3) p3 = bv; else p4 = bv;
    }

    // ---------------- finalize + fold (lane = pixel) ----------------
    {
        Geo G; setup_geo(p0, p1, p2, p3, p4, G);
        const int pr = lane >> 3, pc = lane & 7;
        float xg = s_lin[pc], yg = s_lin[pr];
        float d13, d42;                         // pre-scaled (100*d)
        dists_at(G, xg, yg, d13, d42);
        float w0, w1, w2;
        wedge_of(d13, d42, w0, w1, w2);
        float i0 = s_img[lg][lane];
        float i1 = s_img[lg][64 + lane];
        float i2 = s_img[lg][128 + lane];

        float r[12] = { w0, w1, w2,
                        i0 * w0, i0 * w1, i0 * w2,
                        i1 * w0, i1 * w1, i1 * w2,
                        i2 * w0, i2 * w1, i2 * w2 };
#pragma unroll
        for (int m = 1; m < 64; m <<= 1) {
#pragma unroll
            for (int j = 0; j < 12; ++j) r[j] += __shfl_xor(r[j], m);
        }
        float col[3][3];
#pragma unroll
        for (int c = 0; c < 3; ++c) {
            col[c][0] = r[3 + c * 3 + 0] / (r[0] + 1e-10f);
            col[c][1] = r[3 + c * 3 + 1] / (r[1] + 1e-10f);
            col[c][2] = r[3 + c * 3 + 2] / (r[2] + 1e-10f);
        }
        float o0 = w0 * col[0][0] + w1 * col[0][1] + w2 * col[0][2];
        float o1 = w0 * col[1][0] + w1 * col[1][1] + w2 * col[1][2];
        float o2 = w0 * col[2][0] + w1 * col[2][1] + w2 * col[2][2];

        // mad on the 100x scale; tt = mad/DELTA = mad_s * (1/(100*0.05))
        float mad = (d13 < 0.0f) ? -d13 : ((d42 < 0.0f) ? fminf(d13, -d42) : fminf(d13, d42));
        float tt = mad * 0.2f;
        float lb = 1.0f / (1.0f + tt * tt);

        const int off = ((hp + pr) << 6) + (wp + pc);
        atomicAdd(&foldP[(b * 3 + 0) * 4096 + off], o0);
        atomicAdd(&foldP[(b * 3 + 1) * 4096 + off], o1);
        atomicAdd(&foldP[(b * 3 + 2) * 4096 + off], o2);
        atomicAdd(&foldG[b * 4096 + off], lb);
    }
}

// ---------------- kernel D: fused output heads (ONE block, LDS staging) -----
static __device__ __forceinline__ float np_count(int tpos) {
    int lo = (tpos - 56 > 0) ? (tpos - 56) : 0;
    int hi = (tpos < 7) ? tpos : 7;
    return (float)(hi - lo + 1);
}

__global__ __launch_bounds__(1024) void head_out(const float* __restrict__ foldP,
                                                 const float* __restrict__ foldG,
                                                 const float* __restrict__ fb_w,
                                                 const float* __restrict__ fb_g,
                                                 const float* __restrict__ fb_b,
                                                 const float* __restrict__ fi_w,
                                                 const float* __restrict__ fi_g,
                                                 const float* __restrict__ fi_b,
                                                 float* __restrict__ out) {
    __shared__ float sB[8192];     // 32 KB
    __shared__ float sI[8192];     // 32 KB
    __shared__ float red[16][4];
    __shared__ float s_sc[4];      // scB, shB, scI, shI
    const int t = threadIdx.x;
    float sb = 0, qb = 0, si = 0, qi = 0;
#pragma unroll
    for (int k = 0; k < 8; ++k) {
        const int e = t + 1024 * k;
        const int b = e >> 12, h = (e >> 6) & 63, w = e & 63;
        const float inv = 1.0f / (np_count(h) * np_count(w));
        float gv = foldG[e] * inv;
        float vb = fb_w[0] * gv + fb_w[1] * gv + fb_w[2] * gv;
        const int off = (h << 6) + w;
        float v0 = foldP[(b * 3 + 0) * 4096 + off] * inv;
        float v1 = foldP[(b * 3 + 1) * 4096 + off] * inv;
        float v2 = foldP[(b * 3 + 2) * 4096 + off] * inv;
        float vi = fi_w[0] * v0 + fi_w[1] * v1 + fi_w[2] * v2;
        sB[e] = vb; sI[e] = vi;
        sb += vb; qb += vb * vb; si += vi; qi += vi * vi;
    }
    sb = wave_sum(sb); qb = wave_sum(qb); si = wave_sum(si); qi = wave_sum(qi);
    const int wid = t >> 6;
    if ((t & 63) == 0) { red[wid][0] = sb; red[wid][1] = qb; red[wid][2] = si; red[wid][3] = qi; }
    __syncthreads();
    if (t == 0) {
        float S = 0, Q = 0, S2 = 0, Q2 = 0;
#pragma unroll
        for (int w = 0; w < 16; ++w) { S += red[w][0]; Q += red[w][1]; S2 += red[w][2]; Q2 += red[w][3]; }
        float meanB = S / 8192.0f,  varB = Q / 8192.0f - meanB * meanB;
        float meanI = S2 / 8192.0f, varI = Q2 / 8192.0f - meanI * meanI;
        float scB = fb_g[0] / sqrtf(varB + 1e-5f);
        float scI = fi_g[0] / sqrtf(varI + 1e-5f);
        s_sc[0] = scB; s_sc[1] = fb_b[0] - meanB * scB;
        s_sc[2] = scI; s_sc[3] = fi_b[0] - meanI * scI;
    }
    __syncthreads();
    const float scB = s_sc[0], shB = s_sc[1], scI = s_sc[2], shI = s_sc[3];
#pragma unroll
    for (int k = 0; k < 8; ++k) {
        const int e = t + 1024 * k;
        out[e]        = siluf(sB[e] * scB + shB);
        out[8192 + e] = siluf(sI[e] * scI + shI);
    }
}

// ---------------- launch (3 dispatches, no memset) ----------------
extern "C" void kernel_launch(void* const* d_in, const int* in_sizes, int n_in,
                              void* d_out, int out_size, void* d_ws, size_t ws_size,
                              hipStream_t stream) {
    (void)in_sizes; (void)n_in; (void)out_size; (void)ws_size;
    const float* x        = (const float*)d_in[0];
    const float* reduce_w = (const float*)d_in[1];
    const float* reduce_g = (const float*)d_in[2];
    const float* reduce_b = (const float*)d_in[3];
    const float* fb_w     = (const float*)d_in[4];
    const float* fb_g     = (const float*)d_in[5];
    const float* fb_b     = (const float*)d_in[6];
    const float* fi_w     = (const float*)d_in[7];
    const float* fi_g     = (const float*)d_in[8];
    const float* fi_b     = (const float*)d_in[9];
    float* ws     = (float*)d_ws;
    float* xr     = ws + XR_OFF;
    float* foldP  = ws + FP_OFF;
    float* foldG  = ws + FG_OFF;
    float* st     = ws + ST_OFF;
    float* out    = (float*)d_out;

    head_in_conv<<<64, 128, 0, stream>>>(x, reduce_w, xr, st, (float4*)foldP);
    mega_kernel<<<(NP_ + 3) / 4, 256, 0, stream>>>(xr, reduce_g, reduce_b, st,
                                                   foldP, foldG);
    head_out<<<1, 1024, 0, stream>>>(foldP, foldG, fb_w, fb_g, fb_b,
                                     fi_w, fi_g, fi_b, out);
}

// Round 12
// 227.376 us; speedup vs baseline: 1.6027x; 1.0439x over previous
//
#include <hip/hip_runtime.h>
#include <math.h>

// ---------------- problem constants ----------------
#define B_    2
#define CIN_  32
#define H_    64
#define W_    64
#define HP_   57
#define WP_   57
#define NP_   (B_*HP_*WP_)     // 6498 patches
#define NVALS_ 31

// workspace layout (floats)
#define XR_OFF   0              // 2*3*64*64 = 24576 (RAW conv output, pre-BN)
#define FP_OFF   24576          // 24576 fold of patches   } contiguous 32768
#define FG_OFF   49152          // 8192  fold of boundaries} (zeroed by conv)
#define ST_OFF   57344          // 768: 128 wave-partials x 6 stats (plain stores)
#define WS_TOTAL 58112

// ---------------- math helpers (faithful to jnp f32 semantics) ----------------
static __device__ __forceinline__ float mod2pi(float x) {
    const float TP = (float)(2.0 * M_PI);
    float m = fmodf(x, TP);
    return (m < 0.0f) ? (m + TP) : m;
}
static __device__ __forceinline__ float pow35f(float t) {
    float t2 = t * t, t4 = t2 * t2, t8 = t4 * t4, t16 = t8 * t8, t32 = t16 * t16;
    return t32 * t2 * t;
}
static __device__ __forceinline__ float siluf(float x) {
    return x / (1.0f + expf(-x));
}
static __device__ __forceinline__ float wave_sum(float v) {
#pragma unroll
    for (int m = 1; m < 64; m <<= 1) v += __shfl_xor(v, m);
    return v;
}
// exact f32 of linspace(-1,1,8)[k], computed in f64 like np.linspace
static __device__ __forceinline__ float lin_of(int k) {
    return (float)(-1.0 + (double)k * (2.0 / 7.0));
}

// pre-scaled line coefficients with the 1/ETA=100 atan scale FOLDED IN.
// (R6/R8: ocml atanf is the cheapest atan on gfx950 — keep it.
//  R10: NEVER pin occupancy via __launch_bounds__ 2nd arg — 830 MB spill.
//  R11: the wave_sum stats preamble, not dxv, caused VGPR 84->104; this
//  version reduces stats via 6 serial LDS-bound threads instead.)
struct Geo {
    float X1, Y1, X3, Y3;     // pair (a1, a3) for d13
    float X4, Y4, X2, Y2;     // pair (a4, a2) for d42
    float sgn13, sgn42, g13, g42, x0, y0;
};

static __device__ void setup_geo(float p0, float p1, float p2, float p3, float p4,
                                 Geo& G) {
    const float PIF = (float)M_PI;
    const float SC = 100.0f;    // 1/ETA folded into the plane coefficients
    float m0 = mod2pi(p0), m1 = mod2pi(p1), m2 = mod2pi(p2);
    float lo = fminf(m0, m1), hi = fmaxf(m0, m1);
    float a1 = fminf(lo, m2);
    float a3 = fmaxf(hi, m2);
    float a2 = fmaxf(fminf(hi, m2), lo);
    float hm = mod2pi(0.5f * (a1 - a3));
    float a4 = 0.5f * (a1 + a3) + ((hm >= PIF) ? PIF : 0.0f);
    float d42 = mod2pi(a2 - a4);
    G.sgn42 = (d42 < PIF) ? 1.0f : -1.0f;
    G.g42 = pow35f(d42 / PIF - 1.0f) * 10.0f;   // TAU(0.1) * 100
    float d13 = mod2pi(a3 - a1);
    G.sgn13 = (d13 < PIF) ? 1.0f : -1.0f;
    G.g13 = pow35f(d13 / PIF - 1.0f) * 10.0f;
    float s1 = sinf(a1), c1 = cosf(a1);
    float s2 = sinf(a2), c2 = cosf(a2);
    float s3 = sinf(a3), c3 = cosf(a3);
    float s4 = sinf(a4), c4 = cosf(a4);
    G.X1 = -G.sgn13 * s1 * SC;  G.Y1 =  G.sgn13 * c1 * SC;
    G.X3 =  G.sgn13 * s3 * SC;  G.Y3 = -G.sgn13 * c3 * SC;
    G.X4 = -G.sgn42 * s4 * SC;  G.Y4 =  G.sgn42 * c4 * SC;
    G.X2 =  G.sgn42 * s2 * SC;  G.Y2 = -G.sgn42 * c2 * SC;
    G.x0 = p3; G.y0 = p4;
}

// returns 100*d13, 100*d42
static __device__ __forceinline__ void dists_at(const Geo& G, float xg, float yg,
                                                float& d13, float& d42) {
    float dx = xg - G.x0, dy = yg - G.y0;
    float u1 = G.X1 * dx + G.Y1 * dy;
    float u3 = G.X3 * dx + G.Y3 * dy;
    float u4 = G.X4 * dx + G.Y4 * dy;
    float u2 = G.X2 * dx + G.Y2 * dy;
    d13 = G.sgn13 * fminf(u1, u3) + G.g13;
    d42 = G.sgn42 * fminf(u4, u2) + G.g42;
}

// inputs are pre-scaled (100*d): atan arg needs no multiply
static __device__ __forceinline__ void wedge_of(float d13s, float d42s,
                                                float& w0, float& w1, float& w2) {
    const float C2OPI = (float)(2.0 / M_PI);
    float hd0 = 0.5f * (1.0f + C2OPI * atanf(d13s));
    float hd1 = 0.5f * (1.0f + C2OPI * atanf(d42s));
    w0 = 1.0f - hd0;
    w1 = hd0 * (1.0f - hd1);
    w2 = hd0 * hd1;
}

// ---------------- kernel A: conv1x1 + BN wave-partials + zero fold buffers --
__global__ __launch_bounds__(128) void head_in_conv(const float* __restrict__ x,
                                                    const float* __restrict__ rw,
                                                    float* __restrict__ xr,
                                                    float* __restrict__ st,
                                                    float4* __restrict__ foldZ) {
    const int e = blockIdx.x * 128 + threadIdx.x;   // 0..8191
    // zero foldP+foldG (32768 floats = 8192 float4, contiguous)
    foldZ[e] = make_float4(0.0f, 0.0f, 0.0f, 0.0f);
    const int b = e >> 12, rem = e & 4095;
    const float* xp = x + (size_t)b * CIN_ * 4096 + rem;
    float a0 = 0.0f, a1 = 0.0f, a2 = 0.0f;
#pragma unroll
    for (int c = 0; c < CIN_; ++c) {
        float xv = xp[c * 4096];
        a0 += rw[c] * xv;
        a1 += rw[32 + c] * xv;
        a2 += rw[64 + c] * xv;
    }
    xr[(b * 3 + 0) * 4096 + rem] = a0;
    xr[(b * 3 + 1) * 4096 + rem] = a1;
    xr[(b * 3 + 2) * 4096 + rem] = a2;
    float s0 = wave_sum(a0), q0 = wave_sum(a0 * a0);
    float s1 = wave_sum(a1), q1 = wave_sum(a1 * a1);
    float s2 = wave_sum(a2), q2 = wave_sum(a2 * a2);
    if ((threadIdx.x & 63) == 0) {
        const int wv = (blockIdx.x << 1) | (threadIdx.x >> 6);  // 0..127
        float* dst = st + wv * 6;
        dst[0] = s0; dst[1] = s1; dst[2] = s2;
        dst[3] = q0; dst[4] = q1; dst[5] = q2;
    }
}

// ---------------- mega kernel: stats-reduce + BN-apply + 5-step + finalize --
// wave = 1 patch; 4 patches / 256-thread block. Stats reduced by 6 threads
// into LDS (register-cheap; R11's wave_sum preamble cost 20 VGPRs of peak).
__global__ __launch_bounds__(256) void mega_kernel(const float* __restrict__ xr,
                                                   const float* __restrict__ gamma,
                                                   const float* __restrict__ beta,
                                                   const float* __restrict__ st,
                                                   float* __restrict__ foldP,
                                                   float* __restrict__ foldG) {
    __shared__ float s_img[4][192];   // 4 patches per block, [c*64 + pix]
    __shared__ float s_lin[8];
    __shared__ float s_st[6];         // reduced BN stats: sum0..2, sq0..2
    const int t = threadIdx.x;
    if (t < 8) s_lin[t] = lin_of(t);
    if (t < 6) {
        float acc = 0.0f;
#pragma unroll 8
        for (int w = 0; w < 128; ++w) acc += st[w * 6 + t];
        s_st[t] = acc;
    }
    __syncthreads();

    const int lg = t >> 6, lane = t & 63;
    const int patch = blockIdx.x * 4 + lg;
    const bool active = (patch < NP_);

    int b = 0, hp = 0, wp = 0;
    if (active) {
        b = patch / (HP_ * WP_);
        int pi = patch - b * (HP_ * WP_);
        hp = pi / WP_; wp = pi - hp * WP_;
        const int pr = lane >> 3, pc = lane & 7;
        const int goff = ((hp + pr) << 6) + (wp + pc);
        float mean0 = s_st[0] / 8192.0f, var0 = s_st[3] / 8192.0f - mean0 * mean0;
        float mean1 = s_st[1] / 8192.0f, var1 = s_st[4] / 8192.0f - mean1 * mean1;
        float mean2 = s_st[2] / 8192.0f, var2 = s_st[5] / 8192.0f - mean2 * mean2;
        float sc0 = gamma[0] / sqrtf(var0 + 1e-5f), sh0 = beta[0] - mean0 * sc0;
        float sc1 = gamma[1] / sqrtf(var1 + 1e-5f), sh1 = beta[1] - mean1 * sc1;
        float sc2 = gamma[2] / sqrtf(var2 + 1e-5f), sh2 = beta[2] - mean2 * sc2;
        s_img[lg][lane]       = siluf(xr[((b * 3 + 0) << 12) + goff] * sc0 + sh0);
        s_img[lg][64 + lane]  = siluf(xr[((b * 3 + 1) << 12) + goff] * sc1 + sh1);
        s_img[lg][128 + lane] = siluf(xr[((b * 3 + 2) << 12) + goff] * sc2 + sh2);
    }
    __syncthreads();
    if (!active) return;

    const int cand = lane >> 1;     // 0..31 (31 is padding)
    const int half = lane & 1;      // pixel-half
    const float* img = s_img[lg] + half * 32;
    const int yoff = half << 2;

    // patch sums: candidate- and step-invariant — computed ONCE
    float is0 = 0, is1 = 0, is2 = 0;
#pragma unroll
    for (int i = 0; i < 32; ++i) {
        is0 += img[i]; is1 += img[64 + i]; is2 += img[128 + i];
    }
    is0 += __shfl_xor(is0, 1); is1 += __shfl_xor(is1, 1); is2 += __shfl_xor(is2, 1);

    float p0 = 0.0f, p1 = 0.0f, p2 = 0.0f, p3 = 0.0f, p4 = 0.0f;

#pragma unroll 1
    for (int step = 0; step < 5; ++step) {
        const float base = (step == 0) ? p0 : (step == 1) ? p1 :
                           (step == 2) ? p2 : (step == 3) ? p3 : p4;
        const int ci = (cand < NVALS_) ? cand : (NVALS_ - 1);
        float add;
        if (step < 3) add = (float)((double)ci * (6.283185307179586476925286766559 / 31.0));
        else          add = (float)(-3.0 + (double)ci * 0.2);
        const float pv = base + add;
        Geo G;
        setup_geo((step == 0) ? pv : p0, (step == 1) ? pv : p1,
                  (step == 2) ? pv : p2, (step == 3) ? pv : p3,
                  (step == 4) ? pv : p4, G);

        float ws0 = 0, ws1 = 0;
        float cn00 = 0, cn01 = 0, cn10 = 0, cn11 = 0, cn20 = 0, cn21 = 0;
        float g00 = 0, g01 = 0, g11 = 0;
#pragma unroll 1
        for (int r = 0; r < 4; ++r) {
            const float yg = s_lin[yoff + r];
            const float dy = yg - G.y0;
            const float t1 = G.Y1 * dy, t3 = G.Y3 * dy;
            const float t4 = G.Y4 * dy, t2 = G.Y2 * dy;
#pragma unroll
            for (int cth = 0; cth < 8; ++cth) {
                const int i = r * 8 + cth;
                const float dx = s_lin[cth] - G.x0;    // LDS broadcast, cheap
                float u1 = G.X1 * dx + t1;
                float u3 = G.X3 * dx + t3;
                float u4 = G.X4 * dx + t4;
                float u2 = G.X2 * dx + t2;
                float d13 = G.sgn13 * fminf(u1, u3) + G.g13;   // pre-scaled
                float d42 = G.sgn42 * fminf(u4, u2) + G.g42;
                float w0, w1, w2;
                wedge_of(d13, d42, w0, w1, w2);
                float i0 = img[i], i1 = img[64 + i], i2 = img[128 + i];
                ws0 += w0; ws1 += w1;
                cn00 += i0 * w0; cn01 += i0 * w1;
                cn10 += i1 * w0; cn11 += i1 * w1;
                cn20 += i2 * w0; cn21 += i2 * w1;
                g00 += w0 * w0; g01 += w0 * w1; g11 += w1 * w1;
            }
        }
        // combine pixel-halves (xor-1: cheap swizzle path)
        ws0 += __shfl_xor(ws0, 1); ws1 += __shfl_xor(ws1, 1);
        cn00 += __shfl_xor(cn00, 1); cn01 += __shfl_xor(cn01, 1);
        cn10 += __shfl_xor(cn10, 1); cn11 += __shfl_xor(cn11, 1);
        cn20 += __shfl_xor(cn20, 1); cn21 += __shfl_xor(cn21, 1);
        g00 += __shfl_xor(g00, 1); g01 += __shfl_xor(g01, 1); g11 += __shfl_xor(g11, 1);

        // derive dependent sums (partition of unity)
        float ws2  = 64.0f - ws0 - ws1;
        float cn02 = is0 - cn00 - cn01;
        float cn12 = is1 - cn10 - cn11;
        float cn22 = is2 - cn20 - cn21;
        float g02  = ws0 - g00 - g01;
        float g12  = ws1 - g01 - g11;
        float g22  = ws2 - g02 - g12;

        float r0 = 1.0f / (ws0 + 1e-10f);
        float r1 = 1.0f / (ws1 + 1e-10f);
        float r2 = 1.0f / (ws2 + 1e-10f);
        float c00 = cn00 * r0, c01 = cn01 * r1, c02 = cn02 * r2;
        float c10 = cn10 * r0, c11 = cn11 * r1, c12 = cn12 * r2;
        float c20 = cn20 * r0, c21 = cn21 * r1, c22 = cn22 * r2;

        // loss' = col^T G col - 2 col.cn (constant Sum(i^2) dropped)
        float loss =
            (c00 * c00 * g00 + c01 * c01 * g11 + c02 * c02 * g22
             + 2.0f * (c00 * c01 * g01 + c00 * c02 * g02 + c01 * c02 * g12)
             - 2.0f * (c00 * cn00 + c01 * cn01 + c02 * cn02))
          + (c10 * c10 * g00 + c11 * c11 * g11 + c12 * c12 * g22
             + 2.0f * (c10 * c11 * g01 + c10 * c12 * g02 + c11 * c12 * g12)
             - 2.0f * (c10 * cn10 + c11 * cn11 + c12 * cn12))
          + (c20 * c20 * g00 + c21 * c21 * g11 + c22 * c22 * g22
             + 2.0f * (c20 * c21 * g01 + c20 * c22 * g02 + c21 * c22 * g12)
             - 2.0f * (c20 * cn20 + c21 * cn21 + c22 * cn22));
        if (cand >= NVALS_) loss = INFINITY;

        // argmin over the wave (half-pairs identical; ties -> lower cand)
        float bl = loss; int bi = cand;
#pragma unroll
        for (int off = 32; off > 0; off >>= 1) {
            float ol = __shfl_down(bl, (unsigned)off);
            int   oi = __shfl_down(bi, (unsigned)off);
            if (ol < bl || (ol == bl && oi < bi)) { bl = ol; bi = oi; }
        }
        bi = __shfl(bi, 0);   // broadcast winner to all lanes
        float badd;
        if (step < 3) badd = (float)((double)bi * (6.283185307179586476925286766559 / 31.0));
        else          badd = (float)(-3.0 + (double)bi * 0.2);
        const float bv = base + badd;
        if (step == 0) p0 = bv; else if (step == 1) p1 = bv;
        else if (step == 2) p2 = bv; else if (step == 3) p3 = bv; else p4 = bv;
    }

    // ---------------- finalize + fold (lane = pixel) ----------------
    {
        Geo G; setup_geo(p0, p1, p2, p3, p4, G);
        const int pr = lane >> 3, pc = lane & 7;
        float xg = s_lin[pc], yg = s_lin[pr];
        float d13, d42;                         // pre-scaled (100*d)
        dists_at(G, xg, yg, d13, d42);
        float w0, w1, w2;
        wedge_of(d13, d42, w0, w1, w2);
        float i0 = s_img[lg][lane];
        float i1 = s_img[lg][64 + lane];
        float i2 = s_img[lg][128 + lane];

        float r[12] = { w0, w1, w2,
                        i0 * w0, i0 * w1, i0 * w2,
                        i1 * w0, i1 * w1, i1 * w2,
                        i2 * w0, i2 * w1, i2 * w2 };
#pragma unroll
        for (int m = 1; m < 64; m <<= 1) {
#pragma unroll
            for (int j = 0; j < 12; ++j) r[j] += __shfl_xor(r[j], m);
        }
        float col[3][3];
#pragma unroll
        for (int c = 0; c < 3; ++c) {
            col[c][0] = r[3 + c * 3 + 0] / (r[0] + 1e-10f);
            col[c][1] = r[3 + c * 3 + 1] / (r[1] + 1e-10f);
            col[c][2] = r[3 + c * 3 + 2] / (r[2] + 1e-10f);
        }
        float o0 = w0 * col[0][0] + w1 * col[0][1] + w2 * col[0][2];
        float o1 = w0 * col[1][0] + w1 * col[1][1] + w2 * col[1][2];
        float o2 = w0 * col[2][0] + w1 * col[2][1] + w2 * col[2][2];

        // mad on the 100x scale; tt = mad/DELTA = mad_s * (1/(100*0.05))
        float mad = (d13 < 0.0f) ? -d13 : ((d42 < 0.0f) ? fminf(d13, -d42) : fminf(d13, d42));
        float tt = mad * 0.2f;
        float lb = 1.0f / (1.0f + tt * tt);

        const int off = ((hp + pr) << 6) + (wp + pc);
        atomicAdd(&foldP[(b * 3 + 0) * 4096 + off], o0);
        atomicAdd(&foldP[(b * 3 + 1) * 4096 + off], o1);
        atomicAdd(&foldP[(b * 3 + 2) * 4096 + off], o2);
        atomicAdd(&foldG[b * 4096 + off], lb);
    }
}

// ---------------- kernel D: fused output heads (ONE block, LDS staging) -----
static __device__ __forceinline__ float np_count(int tpos) {
    int lo = (tpos - 56 > 0) ? (tpos - 56) : 0;
    int hi = (tpos < 7) ? tpos : 7;
    return (float)(hi - lo + 1);
}

__global__ __launch_bounds__(1024) void head_out(const float* __restrict__ foldP,
                                                 const float* __restrict__ foldG,
                                                 const float* __restrict__ fb_w,
                                                 const float* __restrict__ fb_g,
                                                 const float* __restrict__ fb_b,
                                                 const float* __restrict__ fi_w,
                                                 const float* __restrict__ fi_g,
                                                 const float* __restrict__ fi_b,
                                                 float* __restrict__ out) {
    __shared__ float sB[8192];     // 32 KB
    __shared__ float sI[8192];     // 32 KB
    __shared__ float red[16][4];
    __shared__ float s_sc[4];      // scB, shB, scI, shI
    const int t = threadIdx.x;
    float sb = 0, qb = 0, si = 0, qi = 0;
#pragma unroll
    for (int k = 0; k < 8; ++k) {
        const int e = t + 1024 * k;
        const int b = e >> 12, h = (e >> 6) & 63, w = e & 63;
        const float inv = 1.0f / (np_count(h) * np_count(w));
        float gv = foldG[e] * inv;
        float vb = fb_w[0] * gv + fb_w[1] * gv + fb_w[2] * gv;
        const int off = (h << 6) + w;
        float v0 = foldP[(b * 3 + 0) * 4096 + off] * inv;
        float v1 = foldP[(b * 3 + 1) * 4096 + off] * inv;
        float v2 = foldP[(b * 3 + 2) * 4096 + off] * inv;
        float vi = fi_w[0] * v0 + fi_w[1] * v1 + fi_w[2] * v2;
        sB[e] = vb; sI[e] = vi;
        sb += vb; qb += vb * vb; si += vi; qi += vi * vi;
    }
    sb = wave_sum(sb); qb = wave_sum(qb); si = wave_sum(si); qi = wave_sum(qi);
    const int wid = t >> 6;
    if ((t & 63) == 0) { red[wid][0] = sb; red[wid][1] = qb; red[wid][2] = si; red[wid][3] = qi; }
    __syncthreads();
    if (t == 0) {
        float S = 0, Q = 0, S2 = 0, Q2 = 0;
#pragma unroll
        for (int w = 0; w < 16; ++w) { S += red[w][0]; Q += red[w][1]; S2 += red[w][2]; Q2 += red[w][3]; }
        float meanB = S / 8192.0f,  varB = Q / 8192.0f - meanB * meanB;
        float meanI = S2 / 8192.0f, varI = Q2 / 8192.0f - meanI * meanI;
        float scB = fb_g[0] / sqrtf(varB + 1e-5f);
        float scI = fi_g[0] / sqrtf(varI + 1e-5f);
        s_sc[0] = scB; s_sc[1] = fb_b[0] - meanB * scB;
        s_sc[2] = scI; s_sc[3] = fi_b[0] - meanI * scI;
    }
    __syncthreads();
    const float scB = s_sc[0], shB = s_sc[1], scI = s_sc[2], shI = s_sc[3];
#pragma unroll
    for (int k = 0; k < 8; ++k) {
        const int e = t + 1024 * k;
        out[e]        = siluf(sB[e] * scB + shB);
        out[8192 + e] = siluf(sI[e] * scI + shI);
    }
}

// ---------------- launch (3 dispatches, no memset) ----------------
extern "C" void kernel_launch(void* const* d_in, const int* in_sizes, int n_in,
                              void* d_out, int out_size, void* d_ws, size_t ws_size,
                              hipStream_t stream) {
    (void)in_sizes; (void)n_in; (void)out_size; (void)ws_size;
    const float* x        = (const float*)d_in[0];
    const float* reduce_w = (const float*)d_in[1];
    const float* reduce_g = (const float*)d_in[2];
    const float* reduce_b = (const float*)d_in[3];
    const float* fb_w     = (const float*)d_in[4];
    const float* fb_g     = (const float*)d_in[5];
    const float* fb_b     = (const float*)d_in[6];
    const float* fi_w     = (const float*)d_in[7];
    const float* fi_g     = (const float*)d_in[8];
    const float* fi_b     = (const float*)d_in[9];
    float* ws     = (float*)d_ws;
    float* xr     = ws + XR_OFF;
    float* foldP  = ws + FP_OFF;
    float* foldG  = ws + FG_OFF;
    float* st     = ws + ST_OFF;
    float* out    = (float*)d_out;

    head_in_conv<<<64, 128, 0, stream>>>(x, reduce_w, xr, st, (float4*)foldP);
    mega_kernel<<<(NP_ + 3) / 4, 256, 0, stream>>>(xr, reduce_g, reduce_b, st,
                                                   foldP, foldG);
    head_out<<<1, 1024, 0, stream>>>(foldP, foldG, fb_w, fb_g, fb_b,
                                     fi_w, fi_g, fi_b, out);
}